// Round 2
// baseline (3432.623 us; speedup 1.0000x reference)
//
#include <hip/hip_runtime.h>
#include <math.h>

#define S_LEN 2048
#define D_MODEL 1024
#define NH 16
#define DK 64
#define BATCH 4

// ---------------------------------------------------------------------------
// Tiled fp32 GEMM: out = X (MxK) @ W^T   (W is NxK row-major, K=N=1024)
// 64x64 tile, BK=32, 256 threads, 4x4 per thread.
// mode 0: plain row-major MxN output (final Wo projection -> d_out)
// mode 1: output to (b,h,s,dk) layout with RoPE applied   (Q, K)
// mode 2: output to (b,h,s,dk) layout, no RoPE            (V)
// ---------------------------------------------------------------------------
__global__ __launch_bounds__(256) void proj_kernel(
    const float* __restrict__ X, const float* __restrict__ W,
    const int* __restrict__ tp, float* __restrict__ out, int mode)
{
    __shared__ float As[64][33];
    __shared__ float Bs[64][33];

    const int K = D_MODEL;
    const int m0 = blockIdx.y * 64;
    const int n0 = blockIdx.x * 64;
    const int tid = threadIdx.x;
    const int ty = tid >> 4;   // 0..15
    const int tx = tid & 15;   // 0..15

    float acc[4][4] = {};

    for (int k0 = 0; k0 < K; k0 += 32) {
        for (int l = tid; l < 64 * 32; l += 256) {
            int r = l >> 5, c = l & 31;
            As[r][c] = X[(size_t)(m0 + r) * K + k0 + c];
            Bs[r][c] = W[(size_t)(n0 + r) * K + k0 + c];
        }
        __syncthreads();
#pragma unroll
        for (int kk = 0; kk < 32; ++kk) {
            float a[4], b[4];
#pragma unroll
            for (int i = 0; i < 4; ++i) a[i] = As[ty * 4 + i][kk];
#pragma unroll
            for (int j = 0; j < 4; ++j) b[j] = Bs[tx * 4 + j][kk];
#pragma unroll
            for (int i = 0; i < 4; ++i)
#pragma unroll
                for (int j = 0; j < 4; ++j) acc[i][j] += a[i] * b[j];
        }
        __syncthreads();
    }

    // Epilogue
    if (mode == 0) {
#pragma unroll
        for (int i = 0; i < 4; ++i) {
            int rg = m0 + ty * 4 + i;
#pragma unroll
            for (int j = 0; j < 4; ++j) {
                int cg = n0 + tx * 4 + j;
                out[(size_t)rg * D_MODEL + cg] = acc[i][j];
            }
        }
        return;
    }

#pragma unroll
    for (int i = 0; i < 4; ++i) {
        int rg = m0 + ty * 4 + i;          // global row = b*S + s
        int bi = rg >> 11;                 // / 2048
        int si = rg & (S_LEN - 1);
        float pos = (float)tp[si];
        int cbase = n0 + tx * 4;           // multiple of 4 -> pairs aligned
#pragma unroll
        for (int j = 0; j < 4; j += 2) {
            int cg = cbase + j;
            int head = cg >> 6;
            int t = cg & 63;               // even
            float xe = acc[i][j];
            float xo = acc[i][j + 1];
            float oe, oo;
            if (mode == 1) {
                float freq = powf(10000.0f, -(float)t / 64.0f);
                float ang = pos * freq;
                float c = cosf(ang), s = sinf(ang);
                oe = c * xe - s * xo;
                oo = s * xe + c * xo;
            } else {
                oe = xe; oo = xo;
            }
            size_t base = (((size_t)bi * NH + head) * S_LEN + si) * DK + t;
            out[base] = oe;
            out[base + 1] = oo;
        }
    }
}

// ---------------------------------------------------------------------------
// Flash-style causal attention, fp32. Bq=Bk=64, 256 threads, 4x4/thread.
// Q,K,V layout: (b,h,s,dk). Output: (b,s,h*dk) = (b,s,d) row-major.
// ---------------------------------------------------------------------------
__global__ __launch_bounds__(256) void attn_kernel(
    const float* __restrict__ Q, const float* __restrict__ K,
    const float* __restrict__ V, float* __restrict__ out)
{
    __shared__ float Qs[64][65];
    __shared__ float KPs[64][65];   // K tile, reused as P tile
    __shared__ float Vs[64][64];
    __shared__ float red[64][16];
    __shared__ float m_s[64], l_s[64], alpha_s[64];

    const int bh = blockIdx.y;          // = bi*NH + head
    const int q0 = blockIdx.x * 64;
    const int tid = threadIdx.x;
    const int ty = tid >> 4;
    const int tx = tid & 15;

    const float* Qb = Q + ((size_t)bh * S_LEN + q0) * DK;
    const float* Kb = K + (size_t)bh * S_LEN * DK;
    const float* Vb = V + (size_t)bh * S_LEN * DK;

    for (int l = tid; l < 64 * 64; l += 256) {
        int r = l >> 6, c = l & 63;
        Qs[r][c] = Qb[r * DK + c] * 0.125f;   // fold 1/sqrt(dk) into Q
    }
    if (tid < 64) { m_s[tid] = -1e30f; l_s[tid] = 0.0f; }
    float o[4][4] = {};
    __syncthreads();

    for (int k0 = 0; k0 <= q0; k0 += 64) {
        for (int l = tid; l < 64 * 64; l += 256) {
            int r = l >> 6, c = l & 63;
            KPs[r][c] = Kb[(size_t)(k0 + r) * DK + c];
            Vs[r][c] = Vb[(size_t)(k0 + r) * DK + c];
        }
        __syncthreads();

        // S = Q K^T (scaled)
        float s[4][4] = {};
#pragma unroll
        for (int kk = 0; kk < 64; ++kk) {
            float a[4], b[4];
#pragma unroll
            for (int i = 0; i < 4; ++i) a[i] = Qs[ty * 4 + i][kk];
#pragma unroll
            for (int j = 0; j < 4; ++j) b[j] = KPs[tx * 4 + j][kk];
#pragma unroll
            for (int i = 0; i < 4; ++i)
#pragma unroll
                for (int j = 0; j < 4; ++j) s[i][j] += a[i] * b[j];
        }

        // causal mask (only the diagonal tile is partial)
        if (k0 == q0) {
#pragma unroll
            for (int i = 0; i < 4; ++i)
#pragma unroll
                for (int j = 0; j < 4; ++j)
                    if (k0 + tx * 4 + j > q0 + ty * 4 + i) s[i][j] = -1e30f;
        }

        // per-row tile max -> red
#pragma unroll
        for (int i = 0; i < 4; ++i) {
            float mx = fmaxf(fmaxf(s[i][0], s[i][1]), fmaxf(s[i][2], s[i][3]));
            red[ty * 4 + i][tx] = mx;
        }
        __syncthreads();

        if (tid < 64) {
            float mx = red[tid][0];
#pragma unroll
            for (int t = 1; t < 16; ++t) mx = fmaxf(mx, red[tid][t]);
            float mo = m_s[tid];
            float mn = fmaxf(mo, mx);
            m_s[tid] = mn;
            float al = expf(mo - mn);
            alpha_s[tid] = al;
            l_s[tid] *= al;
        }
        __syncthreads();

        // P = exp(S - m); write P into KPs (K tile fully consumed); row sums
#pragma unroll
        for (int i = 0; i < 4; ++i) {
            int row = ty * 4 + i;
            float mn = m_s[row];
            float al = alpha_s[row];
            float rs = 0.0f;
#pragma unroll
            for (int j = 0; j < 4; ++j) {
                float p = expf(s[i][j] - mn);
                KPs[row][tx * 4 + j] = p;
                rs += p;
                o[i][j] *= al;
            }
            red[row][tx] = rs;
        }
        __syncthreads();

        if (tid < 64) {
            float sm = 0.0f;
#pragma unroll
            for (int t = 0; t < 16; ++t) sm += red[tid][t];
            l_s[tid] += sm;
        }

        // O += P @ V
#pragma unroll 8
        for (int jj = 0; jj < 64; ++jj) {
            float p[4], v[4];
#pragma unroll
            for (int i = 0; i < 4; ++i) p[i] = KPs[ty * 4 + i][jj];
#pragma unroll
            for (int j = 0; j < 4; ++j) v[j] = Vs[jj][tx * 4 + j];
#pragma unroll
            for (int i = 0; i < 4; ++i)
#pragma unroll
                for (int j = 0; j < 4; ++j) o[i][j] += p[i] * v[j];
        }
        __syncthreads();
    }

    // epilogue: normalize, write (b, s, h, dk)
    const int bi = bh / NH;
    const int head = bh % NH;
#pragma unroll
    for (int i = 0; i < 4; ++i) {
        int q = q0 + ty * 4 + i;
        float inv = 1.0f / l_s[ty * 4 + i];
#pragma unroll
        for (int j = 0; j < 4; ++j) {
            int col = tx * 4 + j;
            out[((size_t)bi * S_LEN + q) * D_MODEL + head * DK + col] = o[i][j] * inv;
        }
    }
}

extern "C" void kernel_launch(void* const* d_in, const int* in_sizes, int n_in,
                              void* d_out, int out_size, void* d_ws, size_t ws_size,
                              hipStream_t stream) {
    const float* x  = (const float*)d_in[0];
    const float* Wq = (const float*)d_in[1];
    const float* Wk = (const float*)d_in[2];
    const float* Wv = (const float*)d_in[3];
    const float* Wo = (const float*)d_in[4];
    const int*   tp = (const int*)d_in[5];
    float* out = (float*)d_out;
    float* ws  = (float*)d_ws;

    const size_t n = (size_t)BATCH * S_LEN * D_MODEL;   // 8.39M floats
    float* Qb = ws;
    float* Kb = ws + n;
    float* Vb = ws + 2 * n;
    float* Ab = ws + 3 * n;

    dim3 blk(256);
    dim3 gproj(D_MODEL / 64, (BATCH * S_LEN) / 64);     // (16, 128)
    proj_kernel<<<gproj, blk, 0, stream>>>(x, Wq, tp, Qb, 1);
    proj_kernel<<<gproj, blk, 0, stream>>>(x, Wk, tp, Kb, 1);
    proj_kernel<<<gproj, blk, 0, stream>>>(x, Wv, tp, Vb, 2);

    dim3 gattn(S_LEN / 64, BATCH * NH);                 // (32, 64)
    attn_kernel<<<gattn, blk, 0, stream>>>(Qb, Kb, Vb, Ab);

    proj_kernel<<<gproj, blk, 0, stream>>>(Ab, Wo, tp, out, 0);
}

// Round 3
// 3174.765 us; speedup vs baseline: 1.0812x; 1.0812x over previous
//
#include <hip/hip_runtime.h>
#include <math.h>

#define S_LEN 2048
#define D_MODEL 1024
#define NH 16
#define DK 64
#define BATCH 4

// log2(10000)/64
#define ROPE_L2F 0.20762050593046014f

// ---------------------------------------------------------------------------
// fp32 GEMM: out = X (MxK) @ W^T, K=N=1024. 128x128 tile, BK=32, 256 thr,
// 8x8 per thread with STRIDED fragments (row = ty+i*16, col = tx+j*16) so
// float4 LDS reads are bank-conflict-free (pad 36 => stride*4 mod 32 = 16,
// tx*36 mod 32 = tx*4 -> 8 start banks x 2-way = free).
// mode 0: row-major MxN output; mode 1: (b,h,s,dk)+RoPE; mode 2: (b,h,s,dk)
// ---------------------------------------------------------------------------
__global__ __launch_bounds__(256) void proj_kernel(
    const float* __restrict__ X, const float* __restrict__ W,
    const int* __restrict__ tp, float* __restrict__ out, int mode)
{
    __shared__ float As[128][36];
    __shared__ float Bs[128][36];

    const int m0 = blockIdx.y * 128;
    const int n0 = blockIdx.x * 128;
    const int tid = threadIdx.x;
    const int ty = tid >> 4;        // 0..15
    const int tx = tid & 15;        // 0..15
    const int lr = tid >> 3;        // 0..31  (loader row)
    const int lc = (tid & 7) * 4;   // 0..28  (loader col, float4)

    float acc[8][8] = {};

    for (int k0 = 0; k0 < D_MODEL; k0 += 32) {
#pragma unroll
        for (int rr = 0; rr < 128; rr += 32) {
            *(float4*)&As[lr + rr][lc] =
                *(const float4*)&X[(size_t)(m0 + lr + rr) * D_MODEL + k0 + lc];
            *(float4*)&Bs[lr + rr][lc] =
                *(const float4*)&W[(size_t)(n0 + lr + rr) * D_MODEL + k0 + lc];
        }
        __syncthreads();
#pragma unroll
        for (int kk = 0; kk < 32; kk += 4) {
            float4 a[8];
#pragma unroll
            for (int i = 0; i < 8; ++i) a[i] = *(const float4*)&As[ty + i * 16][kk];
#pragma unroll
            for (int j = 0; j < 8; ++j) {
                float4 b = *(const float4*)&Bs[tx + j * 16][kk];
#pragma unroll
                for (int i = 0; i < 8; ++i) {
                    acc[i][j] = fmaf(a[i].x, b.x, acc[i][j]);
                    acc[i][j] = fmaf(a[i].y, b.y, acc[i][j]);
                    acc[i][j] = fmaf(a[i].z, b.z, acc[i][j]);
                    acc[i][j] = fmaf(a[i].w, b.w, acc[i][j]);
                }
            }
        }
        __syncthreads();
    }

    if (mode == 0) {
#pragma unroll
        for (int i = 0; i < 8; ++i) {
            int rg = m0 + ty + i * 16;
#pragma unroll
            for (int j = 0; j < 8; ++j)
                out[(size_t)rg * D_MODEL + n0 + tx + j * 16] = acc[i][j];
        }
        return;
    }

    // mode 1/2: write (b,h,s,dk), RoPE for mode 1.
#pragma unroll
    for (int i = 0; i < 8; ++i) {
        int rg = m0 + ty + i * 16;
        int bi = rg >> 11;
        int si = rg & (S_LEN - 1);
        float pos = (float)tp[si];
#pragma unroll
        for (int j = 0; j < 8; ++j) {
            int col = n0 + tx + j * 16;
            int head = col >> 6;
            int tloc = col & 63;
            float v = acc[i][j];
            float res;
            if (mode == 1) {
                float partner = __shfl_xor(v, 1);   // lane tx parity pair
                int tb = tloc & ~1;                 // even element index
                float xe = (tx & 1) ? partner : v;
                float xo = (tx & 1) ? v : partner;
                float freq = exp2f(-(float)tb * ROPE_L2F);
                float ang = pos * freq;
                float s, c;
                __sincosf(ang, &s, &c);
                res = (tx & 1) ? (s * xe + c * xo) : (c * xe - s * xo);
            } else {
                res = v;
            }
            out[(((size_t)bi * NH + head) * S_LEN + si) * DK + tloc] = res;
        }
    }
}

// ---------------------------------------------------------------------------
// Flash causal attention, fp32, Bq=Bk=64, 256 thr.
// QK^T: s rows = ty+i*16 (q), cols = tx+j*16 (k)  [strided, b128-friendly]
// PV:   o rows = ty+i*16 (q), cols = tx*4+j (dv)  [contiguous float4]
// P reuses Ks LDS. Softmax reductions via 16-lane shfl (no idle waves).
// ---------------------------------------------------------------------------
__global__ __launch_bounds__(256) void attn_kernel(
    const float* __restrict__ Q, const float* __restrict__ K,
    const float* __restrict__ V, float* __restrict__ out)
{
    __shared__ float Qs[64][68];
    __shared__ float Ks[64][68];   // reused for P after QK
    __shared__ float Vs[64][68];

    const int bh = blockIdx.y;
    const int q0 = blockIdx.x * 64;
    const int tid = threadIdx.x;
    const int ty = tid >> 4;       // 0..15
    const int tx = tid & 15;       // 0..15

    const float* Qb = Q + ((size_t)bh * S_LEN + q0) * DK;
    const float* Kb = K + (size_t)bh * S_LEN * DK;
    const float* Vb = V + (size_t)bh * S_LEN * DK;

    // load Q tile (scaled by 1/sqrt(dk))
#pragma unroll
    for (int rr = 0; rr < 64; rr += 16) {
        float4 qv = *(const float4*)&Qb[(size_t)(ty + rr) * DK + tx * 4];
        qv.x *= 0.125f; qv.y *= 0.125f; qv.z *= 0.125f; qv.w *= 0.125f;
        *(float4*)&Qs[ty + rr][tx * 4] = qv;
    }

    float o[4][4] = {};
    float m_i[4], l_i[4];
#pragma unroll
    for (int i = 0; i < 4; ++i) { m_i[i] = -1e30f; l_i[i] = 0.0f; }
    __syncthreads();

    for (int k0 = 0; k0 <= q0; k0 += 64) {
#pragma unroll
        for (int rr = 0; rr < 64; rr += 16) {
            *(float4*)&Ks[ty + rr][tx * 4] =
                *(const float4*)&Kb[(size_t)(k0 + ty + rr) * DK + tx * 4];
            *(float4*)&Vs[ty + rr][tx * 4] =
                *(const float4*)&Vb[(size_t)(k0 + ty + rr) * DK + tx * 4];
        }
        __syncthreads();

        // S = Q K^T
        float s[4][4] = {};
#pragma unroll
        for (int kk = 0; kk < DK; kk += 4) {
            float4 a[4];
#pragma unroll
            for (int i = 0; i < 4; ++i) a[i] = *(const float4*)&Qs[ty + i * 16][kk];
#pragma unroll
            for (int j = 0; j < 4; ++j) {
                float4 b = *(const float4*)&Ks[tx + j * 16][kk];
#pragma unroll
                for (int i = 0; i < 4; ++i) {
                    s[i][j] = fmaf(a[i].x, b.x, s[i][j]);
                    s[i][j] = fmaf(a[i].y, b.y, s[i][j]);
                    s[i][j] = fmaf(a[i].z, b.z, s[i][j]);
                    s[i][j] = fmaf(a[i].w, b.w, s[i][j]);
                }
            }
        }

        if (k0 == q0) {   // diagonal tile: causal mask
#pragma unroll
            for (int i = 0; i < 4; ++i)
#pragma unroll
                for (int j = 0; j < 4; ++j)
                    if (tx + j * 16 > ty + i * 16) s[i][j] = -1e30f;
        }
        __syncthreads();   // all QK reads of Ks done; safe to overwrite with P

        // online softmax update + P write (into Ks)
#pragma unroll
        for (int i = 0; i < 4; ++i) {
            float tm = fmaxf(fmaxf(s[i][0], s[i][1]), fmaxf(s[i][2], s[i][3]));
#pragma unroll
            for (int w = 1; w < 16; w <<= 1) tm = fmaxf(tm, __shfl_xor(tm, w));
            float mn = fmaxf(m_i[i], tm);
            float alpha = __expf(m_i[i] - mn);
            m_i[i] = mn;
            float rs = 0.0f;
#pragma unroll
            for (int j = 0; j < 4; ++j) {
                float p = __expf(s[i][j] - mn);
                Ks[ty + i * 16][tx + j * 16] = p;
                rs += p;
            }
#pragma unroll
            for (int w = 1; w < 16; w <<= 1) rs += __shfl_xor(rs, w);
            l_i[i] = l_i[i] * alpha + rs;
#pragma unroll
            for (int j = 0; j < 4; ++j) o[i][j] *= alpha;
        }
        __syncthreads();   // P visible to all

        // O += P @ V
#pragma unroll
        for (int jj = 0; jj < 64; jj += 4) {
            float4 p4[4];
#pragma unroll
            for (int i = 0; i < 4; ++i) p4[i] = *(const float4*)&Ks[ty + i * 16][jj];
#pragma unroll
            for (int u = 0; u < 4; ++u) {
                float4 v4 = *(const float4*)&Vs[jj + u][tx * 4];
                float pu[4] = { p4[0].x, p4[1].x, p4[2].x, p4[3].x };
                if (u == 1) { pu[0] = p4[0].y; pu[1] = p4[1].y; pu[2] = p4[2].y; pu[3] = p4[3].y; }
                if (u == 2) { pu[0] = p4[0].z; pu[1] = p4[1].z; pu[2] = p4[2].z; pu[3] = p4[3].z; }
                if (u == 3) { pu[0] = p4[0].w; pu[1] = p4[1].w; pu[2] = p4[2].w; pu[3] = p4[3].w; }
#pragma unroll
                for (int i = 0; i < 4; ++i) {
                    o[i][0] = fmaf(pu[i], v4.x, o[i][0]);
                    o[i][1] = fmaf(pu[i], v4.y, o[i][1]);
                    o[i][2] = fmaf(pu[i], v4.z, o[i][2]);
                    o[i][3] = fmaf(pu[i], v4.w, o[i][3]);
                }
            }
        }
        __syncthreads();   // PV done before next tile overwrites Ks/Vs
    }

    // epilogue: normalize, write (b, s, d)
    const int bi = bh / NH;
    const int head = bh % NH;
#pragma unroll
    for (int i = 0; i < 4; ++i) {
        int q = q0 + ty + i * 16;
        float inv = 1.0f / l_i[i];
        float4 r;
        r.x = o[i][0] * inv; r.y = o[i][1] * inv;
        r.z = o[i][2] * inv; r.w = o[i][3] * inv;
        *(float4*)&out[((size_t)bi * S_LEN + q) * D_MODEL + head * DK + tx * 4] = r;
    }
}

extern "C" void kernel_launch(void* const* d_in, const int* in_sizes, int n_in,
                              void* d_out, int out_size, void* d_ws, size_t ws_size,
                              hipStream_t stream) {
    const float* x  = (const float*)d_in[0];
    const float* Wq = (const float*)d_in[1];
    const float* Wk = (const float*)d_in[2];
    const float* Wv = (const float*)d_in[3];
    const float* Wo = (const float*)d_in[4];
    const int*   tp = (const int*)d_in[5];
    float* out = (float*)d_out;
    float* ws  = (float*)d_ws;

    const size_t n = (size_t)BATCH * S_LEN * D_MODEL;
    float* Qb = ws;
    float* Kb = ws + n;
    float* Vb = ws + 2 * n;
    float* Ab = ws + 3 * n;

    dim3 blk(256);
    dim3 gproj(D_MODEL / 128, (BATCH * S_LEN) / 128);   // (8, 64)
    proj_kernel<<<gproj, blk, 0, stream>>>(x, Wq, tp, Qb, 1);
    proj_kernel<<<gproj, blk, 0, stream>>>(x, Wk, tp, Kb, 1);
    proj_kernel<<<gproj, blk, 0, stream>>>(x, Wv, tp, Vb, 2);

    dim3 gattn(S_LEN / 64, BATCH * NH);                 // (32, 64)
    attn_kernel<<<gattn, blk, 0, stream>>>(Qb, Kb, Vb, Ab);

    proj_kernel<<<gproj, blk, 0, stream>>>(Ab, Wo, tp, out, 0);
}

// Round 4
// 1578.744 us; speedup vs baseline: 2.1743x; 2.0109x over previous
//
#include <hip/hip_runtime.h>
#include <math.h>

#define S_LEN 2048
#define D_MODEL 1024
#define NH 16
#define DK 64
#define BATCH 4

// log2(10000)/64
#define ROPE_L2F 0.20762050593046014f

typedef __attribute__((ext_vector_type(8))) short bf16x8;
typedef __attribute__((ext_vector_type(4))) float f32x4;

__device__ inline short f2bf(float f) {            // RNE fp32 -> bf16 bits
    unsigned u = __builtin_bit_cast(unsigned, f);
    unsigned r = u + 0x7FFFu + ((u >> 16) & 1u);
    return (short)(r >> 16);
}
__device__ inline float bf2f(short h) {
    unsigned u = ((unsigned)(unsigned short)h) << 16;
    return __builtin_bit_cast(float, u);
}

// ---------------------------------------------------------------------------
// MFMA GEMM: out = X (Mx1024) @ W^T (1024x1024), 16x16x32 bf16 MFMA.
// 128x128 tile, BK=32, 256 thr = 4 waves in 2x2; each wave 64x64 = 4x4 MFMA
// tiles, acc 16 x f32x4. fp32 inputs converted to bf16 (hi) or hi+lo (SPLIT)
// during LDS staging. SPLIT: acc += Ah*Bh + Ah*Bl + Al*Bh (resid ~2^-18).
// LDS rows padded to 40 shorts (80 B): frag b128 reads land 2 lanes/bank.
// MODE 0: row-major out; MODE 1: (b,h,s,dk)+RoPE; MODE 2: (b,h,s,dk).
// Fragment layouts (m89/m97-verified): A/B: [lane&15][quad*8+j];
// C/D: row = quad*4+reg, col = lane&15.
// ---------------------------------------------------------------------------
template<int SPLIT, int MODE>
__global__ __launch_bounds__(256) void proj_mfma(
    const float* __restrict__ X, const float* __restrict__ W,
    const int* __restrict__ tp, float* __restrict__ out)
{
    __shared__ short Ah[128][40];
    __shared__ short Bh[128][40];
    __shared__ short Al[128][40];
    __shared__ short Bl[128][40];

    const int m0 = blockIdx.y * 128;
    const int n0 = blockIdx.x * 128;
    const int tid = threadIdx.x;
    const int lane = tid & 63;
    const int wave = tid >> 6;
    const int quad = lane >> 4;
    const int l16 = lane & 15;
    const int wr = (wave >> 1) * 64;   // wave row offset in tile
    const int wc = (wave & 1) * 64;    // wave col offset in tile
    const int sr = tid >> 1;           // staging row 0..127
    const int sc = (tid & 1) * 16;     // staging col base {0,16}

    f32x4 acc[4][4] = {};

    for (int k0 = 0; k0 < D_MODEL; k0 += 32) {
        // ---- stage X -> Ah/Al, W -> Bh/Bl (16 elems/thread each) ----
        float xv[16], wv[16];
        const float* xp = &X[(size_t)(m0 + sr) * D_MODEL + k0 + sc];
        const float* wp = &W[(size_t)(n0 + sr) * D_MODEL + k0 + sc];
        *(float4*)&xv[0]  = *(const float4*)&xp[0];
        *(float4*)&xv[4]  = *(const float4*)&xp[4];
        *(float4*)&xv[8]  = *(const float4*)&xp[8];
        *(float4*)&xv[12] = *(const float4*)&xp[12];
        *(float4*)&wv[0]  = *(const float4*)&wp[0];
        *(float4*)&wv[4]  = *(const float4*)&wp[4];
        *(float4*)&wv[8]  = *(const float4*)&wp[8];
        *(float4*)&wv[12] = *(const float4*)&wp[12];
        short xh[16], xl[16], wh[16], wl[16];
#pragma unroll
        for (int i = 0; i < 16; ++i) {
            short hx = f2bf(xv[i]); xh[i] = hx;
            short hw = f2bf(wv[i]); wh[i] = hw;
            if (SPLIT) {
                xl[i] = f2bf(xv[i] - bf2f(hx));
                wl[i] = f2bf(wv[i] - bf2f(hw));
            }
        }
        *(bf16x8*)&Ah[sr][sc]     = *(bf16x8*)&xh[0];
        *(bf16x8*)&Ah[sr][sc + 8] = *(bf16x8*)&xh[8];
        *(bf16x8*)&Bh[sr][sc]     = *(bf16x8*)&wh[0];
        *(bf16x8*)&Bh[sr][sc + 8] = *(bf16x8*)&wh[8];
        if (SPLIT) {
            *(bf16x8*)&Al[sr][sc]     = *(bf16x8*)&xl[0];
            *(bf16x8*)&Al[sr][sc + 8] = *(bf16x8*)&xl[8];
            *(bf16x8*)&Bl[sr][sc]     = *(bf16x8*)&wl[0];
            *(bf16x8*)&Bl[sr][sc + 8] = *(bf16x8*)&wl[8];
        }
        __syncthreads();

        // ---- fragments + MFMA ----
        bf16x8 a_h[4], b_h[4];
#pragma unroll
        for (int t = 0; t < 4; ++t) {
            a_h[t] = *(const bf16x8*)&Ah[wr + t * 16 + l16][quad * 8];
            b_h[t] = *(const bf16x8*)&Bh[wc + t * 16 + l16][quad * 8];
        }
#pragma unroll
        for (int mt = 0; mt < 4; ++mt)
#pragma unroll
            for (int nt = 0; nt < 4; ++nt)
                acc[mt][nt] = __builtin_amdgcn_mfma_f32_16x16x32_bf16(
                    a_h[mt], b_h[nt], acc[mt][nt], 0, 0, 0);
        if (SPLIT) {
            bf16x8 b_l[4];
#pragma unroll
            for (int t = 0; t < 4; ++t)
                b_l[t] = *(const bf16x8*)&Bl[wc + t * 16 + l16][quad * 8];
#pragma unroll
            for (int mt = 0; mt < 4; ++mt)
#pragma unroll
                for (int nt = 0; nt < 4; ++nt)
                    acc[mt][nt] = __builtin_amdgcn_mfma_f32_16x16x32_bf16(
                        a_h[mt], b_l[nt], acc[mt][nt], 0, 0, 0);
            bf16x8 a_l[4];
#pragma unroll
            for (int t = 0; t < 4; ++t)
                a_l[t] = *(const bf16x8*)&Al[wr + t * 16 + l16][quad * 8];
#pragma unroll
            for (int mt = 0; mt < 4; ++mt)
#pragma unroll
                for (int nt = 0; nt < 4; ++nt)
                    acc[mt][nt] = __builtin_amdgcn_mfma_f32_16x16x32_bf16(
                        a_l[mt], b_h[nt], acc[mt][nt], 0, 0, 0);
        }
        __syncthreads();
    }

    // ---- epilogue ----
#pragma unroll
    for (int mt = 0; mt < 4; ++mt) {
#pragma unroll
        for (int r = 0; r < 4; ++r) {
            const int row = m0 + wr + mt * 16 + quad * 4 + r;
            if (MODE == 0) {
#pragma unroll
                for (int nt = 0; nt < 4; ++nt) {
                    int col = n0 + wc + nt * 16 + l16;
                    out[(size_t)row * D_MODEL + col] = acc[mt][nt][r];
                }
            } else {
                const int bi = row >> 11;
                const int si = row & (S_LEN - 1);
                float pos = (float)tp[si];
#pragma unroll
                for (int nt = 0; nt < 4; ++nt) {
                    int col = n0 + wc + nt * 16 + l16;
                    int head = col >> 6;
                    int tloc = col & 63;
                    float v = acc[mt][nt][r];
                    float res;
                    if (MODE == 1) {
                        float partner = __shfl_xor(v, 1);   // col parity == lane parity
                        int tb = tloc & ~1;
                        float xe = (lane & 1) ? partner : v;
                        float xo = (lane & 1) ? v : partner;
                        float freq = exp2f(-(float)tb * ROPE_L2F);
                        float ang = pos * freq;
                        float s, c;
                        __sincosf(ang, &s, &c);
                        res = (lane & 1) ? (s * xe + c * xo) : (c * xe - s * xo);
                    } else {
                        res = v;
                    }
                    out[(((size_t)bi * NH + head) * S_LEN + si) * DK + tloc] = res;
                }
            }
        }
    }
}

// ---------------------------------------------------------------------------
// Flash-style causal attention, fp32 (round-2 structure: VGPR ~100,
// measured 1400 us). Bq=Bk=64, 256 threads, 4x4/thread.
// ---------------------------------------------------------------------------
__global__ __launch_bounds__(256) void attn_kernel(
    const float* __restrict__ Q, const float* __restrict__ K,
    const float* __restrict__ V, float* __restrict__ out)
{
    __shared__ float Qs[64][65];
    __shared__ float KPs[64][65];   // K tile, reused as P tile
    __shared__ float Vs[64][64];
    __shared__ float red[64][16];
    __shared__ float m_s[64], l_s[64], alpha_s[64];

    const int bh = blockIdx.y;
    const int q0 = blockIdx.x * 64;
    const int tid = threadIdx.x;
    const int ty = tid >> 4;
    const int tx = tid & 15;

    const float* Qb = Q + ((size_t)bh * S_LEN + q0) * DK;
    const float* Kb = K + (size_t)bh * S_LEN * DK;
    const float* Vb = V + (size_t)bh * S_LEN * DK;

    for (int l = tid; l < 64 * 64; l += 256) {
        int r = l >> 6, c = l & 63;
        Qs[r][c] = Qb[r * DK + c] * 0.125f;
    }
    if (tid < 64) { m_s[tid] = -1e30f; l_s[tid] = 0.0f; }
    float o[4][4] = {};
    __syncthreads();

    for (int k0 = 0; k0 <= q0; k0 += 64) {
        for (int l = tid; l < 64 * 64; l += 256) {
            int r = l >> 6, c = l & 63;
            KPs[r][c] = Kb[(size_t)(k0 + r) * DK + c];
            Vs[r][c] = Vb[(size_t)(k0 + r) * DK + c];
        }
        __syncthreads();

        float s[4][4] = {};
#pragma unroll
        for (int kk = 0; kk < 64; ++kk) {
            float a[4], b[4];
#pragma unroll
            for (int i = 0; i < 4; ++i) a[i] = Qs[ty * 4 + i][kk];
#pragma unroll
            for (int j = 0; j < 4; ++j) b[j] = KPs[tx * 4 + j][kk];
#pragma unroll
            for (int i = 0; i < 4; ++i)
#pragma unroll
                for (int j = 0; j < 4; ++j) s[i][j] += a[i] * b[j];
        }

        if (k0 == q0) {
#pragma unroll
            for (int i = 0; i < 4; ++i)
#pragma unroll
                for (int j = 0; j < 4; ++j)
                    if (k0 + tx * 4 + j > q0 + ty * 4 + i) s[i][j] = -1e30f;
        }

#pragma unroll
        for (int i = 0; i < 4; ++i) {
            float mx = fmaxf(fmaxf(s[i][0], s[i][1]), fmaxf(s[i][2], s[i][3]));
            red[ty * 4 + i][tx] = mx;
        }
        __syncthreads();

        if (tid < 64) {
            float mx = red[tid][0];
#pragma unroll
            for (int t = 1; t < 16; ++t) mx = fmaxf(mx, red[tid][t]);
            float mo = m_s[tid];
            float mn = fmaxf(mo, mx);
            m_s[tid] = mn;
            float al = __expf(mo - mn);
            alpha_s[tid] = al;
            l_s[tid] *= al;
        }
        __syncthreads();

#pragma unroll
        for (int i = 0; i < 4; ++i) {
            int row = ty * 4 + i;
            float mn = m_s[row];
            float al = alpha_s[row];
            float rs = 0.0f;
#pragma unroll
            for (int j = 0; j < 4; ++j) {
                float p = __expf(s[i][j] - mn);
                KPs[row][tx * 4 + j] = p;
                rs += p;
                o[i][j] *= al;
            }
            red[row][tx] = rs;
        }
        __syncthreads();

        if (tid < 64) {
            float sm = 0.0f;
#pragma unroll
            for (int t = 0; t < 16; ++t) sm += red[tid][t];
            l_s[tid] += sm;
        }

#pragma unroll 8
        for (int jj = 0; jj < 64; ++jj) {
            float p[4], v[4];
#pragma unroll
            for (int i = 0; i < 4; ++i) p[i] = KPs[ty * 4 + i][jj];
#pragma unroll
            for (int j = 0; j < 4; ++j) v[j] = Vs[jj][tx * 4 + j];
#pragma unroll
            for (int i = 0; i < 4; ++i)
#pragma unroll
                for (int j = 0; j < 4; ++j) o[i][j] += p[i] * v[j];
        }
        __syncthreads();
    }

    const int bi = bh / NH;
    const int head = bh % NH;
#pragma unroll
    for (int i = 0; i < 4; ++i) {
        int q = q0 + ty * 4 + i;
        float inv = 1.0f / l_s[ty * 4 + i];
#pragma unroll
        for (int j = 0; j < 4; ++j) {
            int col = tx * 4 + j;
            out[((size_t)bi * S_LEN + q) * D_MODEL + head * DK + col] = o[i][j] * inv;
        }
    }
}

extern "C" void kernel_launch(void* const* d_in, const int* in_sizes, int n_in,
                              void* d_out, int out_size, void* d_ws, size_t ws_size,
                              hipStream_t stream) {
    const float* x  = (const float*)d_in[0];
    const float* Wq = (const float*)d_in[1];
    const float* Wk = (const float*)d_in[2];
    const float* Wv = (const float*)d_in[3];
    const float* Wo = (const float*)d_in[4];
    const int*   tp = (const int*)d_in[5];
    float* out = (float*)d_out;
    float* ws  = (float*)d_ws;

    const size_t n = (size_t)BATCH * S_LEN * D_MODEL;
    float* Qb = ws;
    float* Kb = ws + n;
    float* Vb = ws + 2 * n;
    float* Ab = ws + 3 * n;

    dim3 blk(256);
    dim3 gproj(D_MODEL / 128, (BATCH * S_LEN) / 128);   // (8, 64)
    proj_mfma<0, 1><<<gproj, blk, 0, stream>>>(x, Wq, tp, Qb);
    proj_mfma<0, 1><<<gproj, blk, 0, stream>>>(x, Wk, tp, Kb);
    proj_mfma<1, 2><<<gproj, blk, 0, stream>>>(x, Wv, tp, Vb);

    dim3 gattn(S_LEN / 64, BATCH * NH);                 // (32, 64)
    attn_kernel<<<gattn, blk, 0, stream>>>(Qb, Kb, Vb, Ab);

    proj_mfma<1, 0><<<gproj, blk, 0, stream>>>(Ab, Wo, tp, out);
}

// Round 5
// 546.423 us; speedup vs baseline: 6.2820x; 2.8892x over previous
//
#include <hip/hip_runtime.h>
#include <math.h>

#define S_LEN 2048
#define D_MODEL 1024
#define NH 16
#define DK 64
#define BATCH 4

// log2(10000)/64
#define ROPE_L2F 0.20762050593046014f

typedef __attribute__((ext_vector_type(8))) short bf16x8;
typedef __attribute__((ext_vector_type(4))) short short4v;
typedef __attribute__((ext_vector_type(2))) short short2v;
typedef __attribute__((ext_vector_type(4))) float f32x4;

__device__ inline short f2bf(float f) {            // RNE fp32 -> bf16 bits
    unsigned u = __builtin_bit_cast(unsigned, f);
    unsigned r = u + 0x7FFFu + ((u >> 16) & 1u);
    return (short)(r >> 16);
}
__device__ inline float bf2f(short h) {
    unsigned u = ((unsigned)(unsigned short)h) << 16;
    return __builtin_bit_cast(float, u);
}

// ---------------------------------------------------------------------------
// MFMA GEMM: out = X (Mx1024) @ W^T (1024x1024), 16x16x32 bf16 MFMA.
// (unchanged from round 4 — measured ~55us/dispatch, absmax-transparent)
// ---------------------------------------------------------------------------
template<int SPLIT, int MODE>
__global__ __launch_bounds__(256) void proj_mfma(
    const float* __restrict__ X, const float* __restrict__ W,
    const int* __restrict__ tp, float* __restrict__ out)
{
    __shared__ short Ah[128][40];
    __shared__ short Bh[128][40];
    __shared__ short Al[128][40];
    __shared__ short Bl[128][40];

    const int m0 = blockIdx.y * 128;
    const int n0 = blockIdx.x * 128;
    const int tid = threadIdx.x;
    const int lane = tid & 63;
    const int wave = tid >> 6;
    const int quad = lane >> 4;
    const int l16 = lane & 15;
    const int wr = (wave >> 1) * 64;
    const int wc = (wave & 1) * 64;
    const int sr = tid >> 1;
    const int sc = (tid & 1) * 16;

    f32x4 acc[4][4] = {};

    for (int k0 = 0; k0 < D_MODEL; k0 += 32) {
        float xv[16], wv[16];
        const float* xp = &X[(size_t)(m0 + sr) * D_MODEL + k0 + sc];
        const float* wp = &W[(size_t)(n0 + sr) * D_MODEL + k0 + sc];
        *(float4*)&xv[0]  = *(const float4*)&xp[0];
        *(float4*)&xv[4]  = *(const float4*)&xp[4];
        *(float4*)&xv[8]  = *(const float4*)&xp[8];
        *(float4*)&xv[12] = *(const float4*)&xp[12];
        *(float4*)&wv[0]  = *(const float4*)&wp[0];
        *(float4*)&wv[4]  = *(const float4*)&wp[4];
        *(float4*)&wv[8]  = *(const float4*)&wp[8];
        *(float4*)&wv[12] = *(const float4*)&wp[12];
        short xh[16], xl[16], wh[16], wl[16];
#pragma unroll
        for (int i = 0; i < 16; ++i) {
            short hx = f2bf(xv[i]); xh[i] = hx;
            short hw = f2bf(wv[i]); wh[i] = hw;
            if (SPLIT) {
                xl[i] = f2bf(xv[i] - bf2f(hx));
                wl[i] = f2bf(wv[i] - bf2f(hw));
            }
        }
        *(bf16x8*)&Ah[sr][sc]     = *(bf16x8*)&xh[0];
        *(bf16x8*)&Ah[sr][sc + 8] = *(bf16x8*)&xh[8];
        *(bf16x8*)&Bh[sr][sc]     = *(bf16x8*)&wh[0];
        *(bf16x8*)&Bh[sr][sc + 8] = *(bf16x8*)&wh[8];
        if (SPLIT) {
            *(bf16x8*)&Al[sr][sc]     = *(bf16x8*)&xl[0];
            *(bf16x8*)&Al[sr][sc + 8] = *(bf16x8*)&xl[8];
            *(bf16x8*)&Bl[sr][sc]     = *(bf16x8*)&wl[0];
            *(bf16x8*)&Bl[sr][sc + 8] = *(bf16x8*)&wl[8];
        }
        __syncthreads();

        bf16x8 a_h[4], b_h[4];
#pragma unroll
        for (int t = 0; t < 4; ++t) {
            a_h[t] = *(const bf16x8*)&Ah[wr + t * 16 + l16][quad * 8];
            b_h[t] = *(const bf16x8*)&Bh[wc + t * 16 + l16][quad * 8];
        }
#pragma unroll
        for (int mt = 0; mt < 4; ++mt)
#pragma unroll
            for (int nt = 0; nt < 4; ++nt)
                acc[mt][nt] = __builtin_amdgcn_mfma_f32_16x16x32_bf16(
                    a_h[mt], b_h[nt], acc[mt][nt], 0, 0, 0);
        if (SPLIT) {
            bf16x8 b_l[4];
#pragma unroll
            for (int t = 0; t < 4; ++t)
                b_l[t] = *(const bf16x8*)&Bl[wc + t * 16 + l16][quad * 8];
#pragma unroll
            for (int mt = 0; mt < 4; ++mt)
#pragma unroll
                for (int nt = 0; nt < 4; ++nt)
                    acc[mt][nt] = __builtin_amdgcn_mfma_f32_16x16x32_bf16(
                        a_h[mt], b_l[nt], acc[mt][nt], 0, 0, 0);
            bf16x8 a_l[4];
#pragma unroll
            for (int t = 0; t < 4; ++t)
                a_l[t] = *(const bf16x8*)&Al[wr + t * 16 + l16][quad * 8];
#pragma unroll
            for (int mt = 0; mt < 4; ++mt)
#pragma unroll
                for (int nt = 0; nt < 4; ++nt)
                    acc[mt][nt] = __builtin_amdgcn_mfma_f32_16x16x32_bf16(
                        a_l[mt], b_h[nt], acc[mt][nt], 0, 0, 0);
        }
        __syncthreads();
    }

#pragma unroll
    for (int mt = 0; mt < 4; ++mt) {
#pragma unroll
        for (int r = 0; r < 4; ++r) {
            const int row = m0 + wr + mt * 16 + quad * 4 + r;
            if (MODE == 0) {
#pragma unroll
                for (int nt = 0; nt < 4; ++nt) {
                    int col = n0 + wc + nt * 16 + l16;
                    out[(size_t)row * D_MODEL + col] = acc[mt][nt][r];
                }
            } else {
                const int bi = row >> 11;
                const int si = row & (S_LEN - 1);
                float pos = (float)tp[si];
#pragma unroll
                for (int nt = 0; nt < 4; ++nt) {
                    int col = n0 + wc + nt * 16 + l16;
                    int head = col >> 6;
                    int tloc = col & 63;
                    float v = acc[mt][nt][r];
                    float res;
                    if (MODE == 1) {
                        float partner = __shfl_xor(v, 1);
                        int tb = tloc & ~1;
                        float xe = (lane & 1) ? partner : v;
                        float xo = (lane & 1) ? v : partner;
                        float freq = exp2f(-(float)tb * ROPE_L2F);
                        float ang = pos * freq;
                        float s, c;
                        __sincosf(ang, &s, &c);
                        res = (lane & 1) ? (s * xe + c * xo) : (c * xe - s * xo);
                    } else {
                        res = v;
                    }
                    out[(((size_t)bi * NH + head) * S_LEN + si) * DK + tloc] = res;
                }
            }
        }
    }
}

// ---------------------------------------------------------------------------
// MFMA flash causal attention, bf16 inputs / fp32 softmax+acc.
// 256 thr = 4 waves; block = 64 q rows (wave wq owns q = q0+wq*16+l16),
// k-tiles of 64. Trick: compute S^T (A=K,B=Q) and O^T (A=V^T,B=P) so the
// C/D column index (lane&15) is ALWAYS q: softmax m/l/alpha are per-lane
// scalars (2 shfl_xor for cross-quad reduce), P packs to k-contiguous
// short4 ds_write_b64, PV A/B frags are aligned ds_read_b128, O^T epilogue
// is contiguous float4. Ps aliases Qs (Q frags hoisted). LDS 27.6 KB.
// Layouts per m89/m97 (verified by round-4 proj pass):
//   operand frag: Op[outer=lane&15][k = quad*8 + j]; C/D: row=quad*4+reg,
//   col=lane&15.
// ---------------------------------------------------------------------------
#define PADS 72

__global__ __launch_bounds__(256) void attn_mfma(
    const float* __restrict__ Q, const float* __restrict__ K,
    const float* __restrict__ V, float* __restrict__ out)
{
    __shared__ short Qs[64][PADS];   // reused as Ps after Q-frag hoist
    __shared__ short Ks[64][PADS];   // K tile, natural [k][d]
    __shared__ short Vt[64][PADS];   // V tile transposed [d][k]

    const int bh = blockIdx.y;
    const int q0 = blockIdx.x * 64;
    const int tid = threadIdx.x;
    const int wave = tid >> 6;
    const int lane = tid & 63;
    const int quad = lane >> 4;
    const int l16 = lane & 15;

    const float* Qb = Q + ((size_t)bh * S_LEN + q0) * DK;
    const float* Kb = K + (size_t)bh * S_LEN * DK;
    const float* Vb = V + (size_t)bh * S_LEN * DK;

    // ---- stage Q tile as bf16, scale folded (1/sqrt(64) = 0.125) ----
    {
        const int sr = tid >> 2, scb = (tid & 3) * 16;
        float qv[16];
        *(float4*)&qv[0]  = *(const float4*)&Qb[sr * DK + scb];
        *(float4*)&qv[4]  = *(const float4*)&Qb[sr * DK + scb + 4];
        *(float4*)&qv[8]  = *(const float4*)&Qb[sr * DK + scb + 8];
        *(float4*)&qv[12] = *(const float4*)&Qb[sr * DK + scb + 12];
        short qh[16];
#pragma unroll
        for (int i = 0; i < 16; ++i) qh[i] = f2bf(qv[i] * 0.125f);
        *(bf16x8*)&Qs[sr][scb]     = *(bf16x8*)&qh[0];
        *(bf16x8*)&Qs[sr][scb + 8] = *(bf16x8*)&qh[8];
    }
    __syncthreads();

    bf16x8 Qf[2];
#pragma unroll
    for (int c = 0; c < 2; ++c)
        Qf[c] = *(const bf16x8*)&Qs[wave * 16 + l16][c * 32 + quad * 8];
    // Qs is dead from here (every wave read its frags before the next
    // barrier) -> alias Ps onto it. Ps rows are wave-private.
    short (*Ps)[PADS] = Qs;
    const int prow = wave * 16 + l16;

    float m_i = -1e30f, l_i = 0.0f;
    f32x4 o[4] = {};                 // O^T tiles: d = dt*16+quad*4+r, q = l16

    const int ktiles = (q0 >> 6) + 1;
    for (int t = 0; t < ktiles; ++t) {
        const int k0 = t * 64;
        // ---- stage K (natural bf16) ----
        {
            const int sr = tid >> 2, scb = (tid & 3) * 16;
            const float* kp = &Kb[(size_t)(k0 + sr) * DK + scb];
            float kv[16];
            *(float4*)&kv[0]  = *(const float4*)&kp[0];
            *(float4*)&kv[4]  = *(const float4*)&kp[4];
            *(float4*)&kv[8]  = *(const float4*)&kp[8];
            *(float4*)&kv[12] = *(const float4*)&kp[12];
            short kh[16];
#pragma unroll
            for (int i = 0; i < 16; ++i) kh[i] = f2bf(kv[i]);
            *(bf16x8*)&Ks[sr][scb]     = *(bf16x8*)&kh[0];
            *(bf16x8*)&Ks[sr][scb + 8] = *(bf16x8*)&kh[8];

            // ---- stage V transposed: k-pair per thread, short2 stores ----
            const int kp2 = (tid & 31) * 2, db = (tid >> 5) * 8;
            const float* vp0 = &Vb[(size_t)(k0 + kp2) * DK + db];
            const float* vp1 = &Vb[(size_t)(k0 + kp2 + 1) * DK + db];
            float v0[8], v1[8];
            *(float4*)&v0[0] = *(const float4*)&vp0[0];
            *(float4*)&v0[4] = *(const float4*)&vp0[4];
            *(float4*)&v1[0] = *(const float4*)&vp1[0];
            *(float4*)&v1[4] = *(const float4*)&vp1[4];
#pragma unroll
            for (int i = 0; i < 8; ++i) {
                short2v p; p.x = f2bf(v0[i]); p.y = f2bf(v1[i]);
                *(short2v*)&Vt[db + i][kp2] = p;
            }
        }
        __syncthreads();

        // ---- S^T = K Q^T : sT[kt] covers k = k0+kt*16+quad*4+r, q = l16 ----
        f32x4 sT[4] = {};
#pragma unroll
        for (int c = 0; c < 2; ++c) {
#pragma unroll
            for (int kt = 0; kt < 4; ++kt) {
                bf16x8 a = *(const bf16x8*)&Ks[kt * 16 + l16][c * 32 + quad * 8];
                sT[kt] = __builtin_amdgcn_mfma_f32_16x16x32_bf16(
                    a, Qf[c], sT[kt], 0, 0, 0);
            }
        }

        if (k0 == q0) {   // diagonal: causal mask, k > q
            const int qg = wave * 16 + l16;
#pragma unroll
            for (int kt = 0; kt < 4; ++kt)
#pragma unroll
                for (int r = 0; r < 4; ++r)
                    if (kt * 16 + quad * 4 + r > qg) sT[kt][r] = -1e30f;
        }

        // ---- online softmax (per-lane state, quad-reduce via shfl) ----
        float tmax = -1e30f;
#pragma unroll
        for (int kt = 0; kt < 4; ++kt)
#pragma unroll
            for (int r = 0; r < 4; ++r) tmax = fmaxf(tmax, sT[kt][r]);
        tmax = fmaxf(tmax, __shfl_xor(tmax, 16));
        tmax = fmaxf(tmax, __shfl_xor(tmax, 32));
        float mn = fmaxf(m_i, tmax);
        float alpha = __expf(m_i - mn);
        m_i = mn;
        float rs = 0.0f;
#pragma unroll
        for (int kt = 0; kt < 4; ++kt) {
            float p0 = __expf(sT[kt][0] - mn);
            float p1 = __expf(sT[kt][1] - mn);
            float p2 = __expf(sT[kt][2] - mn);
            float p3 = __expf(sT[kt][3] - mn);
            rs += (p0 + p1) + (p2 + p3);
            short4v pk;
            pk.x = f2bf(p0); pk.y = f2bf(p1); pk.z = f2bf(p2); pk.w = f2bf(p3);
            *(short4v*)&Ps[prow][kt * 16 + quad * 4] = pk;   // k-contiguous b64
        }
        rs += __shfl_xor(rs, 16);
        rs += __shfl_xor(rs, 32);
        l_i = l_i * alpha + rs;
#pragma unroll
        for (int dt = 0; dt < 4; ++dt) {
            o[dt][0] *= alpha; o[dt][1] *= alpha;
            o[dt][2] *= alpha; o[dt][3] *= alpha;
        }

        // ---- O^T += V^T P^T  (A = Vt frag, B = P frag; wave-local Ps) ----
        bf16x8 Pf[2];
#pragma unroll
        for (int c = 0; c < 2; ++c)
            Pf[c] = *(const bf16x8*)&Ps[prow][c * 32 + quad * 8];
#pragma unroll
        for (int c = 0; c < 2; ++c)
#pragma unroll
            for (int dt = 0; dt < 4; ++dt) {
                bf16x8 a = *(const bf16x8*)&Vt[dt * 16 + l16][c * 32 + quad * 8];
                o[dt] = __builtin_amdgcn_mfma_f32_16x16x32_bf16(
                    a, Pf[c], o[dt], 0, 0, 0);
            }
        __syncthreads();   // before next tile overwrites Ks/Vt
    }

    // ---- epilogue: normalize rows (q = l16, lane-uniform), store float4 ----
    const int bi = bh >> 4;
    const int head = bh & 15;
    const int q = q0 + wave * 16 + l16;
    const float linv = 1.0f / l_i;
    float* ob = &out[((size_t)bi * S_LEN + q) * D_MODEL + head * DK];
#pragma unroll
    for (int dt = 0; dt < 4; ++dt) {
        float4 r;
        r.x = o[dt][0] * linv; r.y = o[dt][1] * linv;
        r.z = o[dt][2] * linv; r.w = o[dt][3] * linv;
        *(float4*)&ob[dt * 16 + quad * 4] = r;
    }
}

extern "C" void kernel_launch(void* const* d_in, const int* in_sizes, int n_in,
                              void* d_out, int out_size, void* d_ws, size_t ws_size,
                              hipStream_t stream) {
    const float* x  = (const float*)d_in[0];
    const float* Wq = (const float*)d_in[1];
    const float* Wk = (const float*)d_in[2];
    const float* Wv = (const float*)d_in[3];
    const float* Wo = (const float*)d_in[4];
    const int*   tp = (const int*)d_in[5];
    float* out = (float*)d_out;
    float* ws  = (float*)d_ws;

    const size_t n = (size_t)BATCH * S_LEN * D_MODEL;
    float* Qb = ws;
    float* Kb = ws + n;
    float* Vb = ws + 2 * n;
    float* Ab = ws + 3 * n;

    dim3 blk(256);
    dim3 gproj(D_MODEL / 128, (BATCH * S_LEN) / 128);   // (8, 64)
    proj_mfma<0, 1><<<gproj, blk, 0, stream>>>(x, Wq, tp, Qb);
    proj_mfma<0, 1><<<gproj, blk, 0, stream>>>(x, Wk, tp, Kb);
    proj_mfma<1, 2><<<gproj, blk, 0, stream>>>(x, Wv, tp, Vb);

    dim3 gattn(S_LEN / 64, BATCH * NH);                 // (32, 64)
    attn_mfma<<<gattn, blk, 0, stream>>>(Qb, Kb, Vb, Ab);

    proj_mfma<1, 0><<<gproj, blk, 0, stream>>>(Ab, Wo, tp, out);
}

// Round 6
// 446.808 us; speedup vs baseline: 7.6825x; 1.2229x over previous
//
#include <hip/hip_runtime.h>
#include <math.h>

#define S_LEN 2048
#define D_MODEL 1024
#define NH 16
#define DK 64
#define BATCH 4

// log2(10000)/64
#define ROPE_L2F 0.20762050593046014f
// 0.125 * log2(e): folds 1/sqrt(dk) and exp->exp2 conversion into Q
#define QSCALE 0.18033688011112042f

typedef __attribute__((ext_vector_type(8))) short bf16x8;
typedef __attribute__((ext_vector_type(4))) short short4v;
typedef __attribute__((ext_vector_type(2))) short short2v;
typedef __attribute__((ext_vector_type(4))) float f32x4;

__device__ inline short f2bf(float f) {            // RNE fp32 -> bf16 bits
    unsigned u = __builtin_bit_cast(unsigned, f);
    unsigned r = u + 0x7FFFu + ((u >> 16) & 1u);
    return (short)(r >> 16);
}

// ---------------------------------------------------------------------------
// One-time fp32 -> bf16 conversion (x and the four W matrices).
// ---------------------------------------------------------------------------
__global__ __launch_bounds__(256) void conv_bf16(
    const float* __restrict__ src, short* __restrict__ dst, int n)
{
    int i = (blockIdx.x * 256 + threadIdx.x) * 8;
    if (i >= n) return;
    float4 a = *(const float4*)&src[i];
    float4 b = *(const float4*)&src[i + 4];
    short h[8] = { f2bf(a.x), f2bf(a.y), f2bf(a.z), f2bf(a.w),
                   f2bf(b.x), f2bf(b.y), f2bf(b.z), f2bf(b.w) };
    *(bf16x8*)&dst[i] = *(bf16x8*)h;
}

// ---------------------------------------------------------------------------
// Pure-bf16 MFMA GEMM: C = A (Mx1024) @ B^T (1024x1024), 16x16x32 MFMA,
// 128x128 tile, BK=32, 4 waves 2x2, LDS pad 40 shorts (2-way free).
// MODE 0: fp32 row-major out (Wo).  MODE 1: RoPE*scale -> bf16 (b,h,s,dk)
// (Q: scale=QSCALE, K: scale=1).    MODE 2: bf16 (b,h,s,dk) (V).
// ---------------------------------------------------------------------------
template<int MODE>
__global__ __launch_bounds__(256) void proj_bf16(
    const short* __restrict__ A, const short* __restrict__ Bw,
    const int* __restrict__ tp, float* __restrict__ outf,
    short* __restrict__ outh, float scale)
{
    __shared__ short As[128][40];
    __shared__ short Bs[128][40];

    const int m0 = blockIdx.y * 128;
    const int n0 = blockIdx.x * 128;
    const int tid = threadIdx.x;
    const int lane = tid & 63;
    const int wave = tid >> 6;
    const int quad = lane >> 4;
    const int l16 = lane & 15;
    const int wr = (wave >> 1) * 64;
    const int wc = (wave & 1) * 64;
    const int sr = tid >> 1;
    const int sc = (tid & 1) * 16;

    f32x4 acc[4][4] = {};

    for (int k0 = 0; k0 < D_MODEL; k0 += 32) {
        const short* ap = &A[(size_t)(m0 + sr) * D_MODEL + k0 + sc];
        const short* bp = &Bw[(size_t)(n0 + sr) * D_MODEL + k0 + sc];
        bf16x8 a0 = *(const bf16x8*)&ap[0];
        bf16x8 a1 = *(const bf16x8*)&ap[8];
        bf16x8 b0 = *(const bf16x8*)&bp[0];
        bf16x8 b1 = *(const bf16x8*)&bp[8];
        *(bf16x8*)&As[sr][sc]     = a0;
        *(bf16x8*)&As[sr][sc + 8] = a1;
        *(bf16x8*)&Bs[sr][sc]     = b0;
        *(bf16x8*)&Bs[sr][sc + 8] = b1;
        __syncthreads();

        bf16x8 a_h[4], b_h[4];
#pragma unroll
        for (int t = 0; t < 4; ++t) {
            a_h[t] = *(const bf16x8*)&As[wr + t * 16 + l16][quad * 8];
            b_h[t] = *(const bf16x8*)&Bs[wc + t * 16 + l16][quad * 8];
        }
#pragma unroll
        for (int mt = 0; mt < 4; ++mt)
#pragma unroll
            for (int nt = 0; nt < 4; ++nt)
                acc[mt][nt] = __builtin_amdgcn_mfma_f32_16x16x32_bf16(
                    a_h[mt], b_h[nt], acc[mt][nt], 0, 0, 0);
        __syncthreads();
    }

#pragma unroll
    for (int mt = 0; mt < 4; ++mt) {
#pragma unroll
        for (int r = 0; r < 4; ++r) {
            const int row = m0 + wr + mt * 16 + quad * 4 + r;
            if (MODE == 0) {
#pragma unroll
                for (int nt = 0; nt < 4; ++nt) {
                    int col = n0 + wc + nt * 16 + l16;
                    outf[(size_t)row * D_MODEL + col] = acc[mt][nt][r];
                }
            } else {
                const int bi = row >> 11;
                const int si = row & (S_LEN - 1);
                float pos = (float)tp[si];
#pragma unroll
                for (int nt = 0; nt < 4; ++nt) {
                    int col = n0 + wc + nt * 16 + l16;
                    int head = col >> 6;
                    int tloc = col & 63;
                    float v = acc[mt][nt][r];
                    float res;
                    if (MODE == 1) {
                        float partner = __shfl_xor(v, 1);
                        int tb = tloc & ~1;
                        float xe = (lane & 1) ? partner : v;
                        float xo = (lane & 1) ? v : partner;
                        float freq = exp2f(-(float)tb * ROPE_L2F);
                        float ang = pos * freq;
                        float s, c;
                        __sincosf(ang, &s, &c);
                        res = ((lane & 1) ? (s * xe + c * xo)
                                          : (c * xe - s * xo)) * scale;
                    } else {
                        res = v;
                    }
                    outh[(((size_t)bi * NH + head) * S_LEN + si) * DK + tloc] =
                        f2bf(res);
                }
            }
        }
    }
}

// ---------------------------------------------------------------------------
// MFMA flash causal attention, bf16 in / bf16 out, exp2-domain softmax
// (log2e pre-folded into Q). Bq=128 (4 waves x 32 q rows), Bk=64.
// S^T = K·Q^T and O^T = V^T·P^T so q rides lane&15 everywhere: softmax is
// per-lane + 2 shfl. Q,K fragments load DIRECTLY from global (aligned 16B,
// L2-served); only V round-trips LDS (transpose). P wave-local via LDS.
// ---------------------------------------------------------------------------
#define PADS 72

__global__ __launch_bounds__(256) void attn_bf16(
    const short* __restrict__ Q, const short* __restrict__ K,
    const short* __restrict__ V, short* __restrict__ O)
{
    __shared__ short Vt[64][PADS];    // V tile transposed [d][k]
    __shared__ short Ps[128][PADS];   // P rows, per-wave-private

    const int bh = blockIdx.y;
    const int bx = (gridDim.x - 1) - blockIdx.x;   // heavy blocks first
    const int q0 = bx * 128;
    const int tid = threadIdx.x;
    const int wave = tid >> 6;
    const int lane = tid & 63;
    const int quad = lane >> 4;
    const int l16 = lane & 15;
    const int qbase = q0 + wave * 32;

    const short* Kb = K + (size_t)bh * S_LEN * DK;
    const short* Vb = V + (size_t)bh * S_LEN * DK;

    // Q fragments straight from global (wave-private rows)
    bf16x8 Qf[2][2];
#pragma unroll
    for (int sub = 0; sub < 2; ++sub)
#pragma unroll
        for (int c = 0; c < 2; ++c)
            Qf[sub][c] = *(const bf16x8*)
                &Q[((size_t)bh * S_LEN + qbase + sub * 16 + l16) * DK +
                   c * 32 + quad * 8];

    float m_i[2] = { -1e30f, -1e30f }, l_i[2] = { 0.0f, 0.0f };
    f32x4 o[2][4] = {};

    const int ktiles = 2 * bx + 2;
    for (int t = 0; t < ktiles; ++t) {
        const int k0 = t * 64;
        // ---- stage V transposed (bf16, 16B loads, short2 scatter) ----
        {
            const int kp2 = (tid & 31) * 2, db = (tid >> 5) * 8;
            const short* vp0 = &Vb[(size_t)(k0 + kp2) * DK + db];
            bf16x8 v0 = *(const bf16x8*)vp0;
            bf16x8 v1 = *(const bf16x8*)(vp0 + DK);
#pragma unroll
            for (int i = 0; i < 8; ++i) {
                short2v p; p.x = v0[i]; p.y = v1[i];
                *(short2v*)&Vt[db + i][kp2] = p;
            }
        }
        __syncthreads();

        if (k0 <= qbase + 31) {        // wave has live q rows for this tile
            // K fragments straight from global
            bf16x8 af[4][2];
#pragma unroll
            for (int kt = 0; kt < 4; ++kt)
#pragma unroll
                for (int c = 0; c < 2; ++c)
                    af[kt][c] = *(const bf16x8*)
                        &Kb[(size_t)(k0 + kt * 16 + l16) * DK + c * 32 + quad * 8];

#pragma unroll
            for (int sub = 0; sub < 2; ++sub) {
                f32x4 sT[4] = {};
#pragma unroll
                for (int c = 0; c < 2; ++c)
#pragma unroll
                    for (int kt = 0; kt < 4; ++kt)
                        sT[kt] = __builtin_amdgcn_mfma_f32_16x16x32_bf16(
                            af[kt][c], Qf[sub][c], sT[kt], 0, 0, 0);

                const int qg = qbase + sub * 16 + l16;
                if (k0 + 63 > qbase + sub * 16) {   // causal mask needed
#pragma unroll
                    for (int kt = 0; kt < 4; ++kt)
#pragma unroll
                        for (int r = 0; r < 4; ++r)
                            if (k0 + kt * 16 + quad * 4 + r > qg)
                                sT[kt][r] = -1e30f;
                }

                // online softmax, exp2 domain, per-lane state
                float tmax = -1e30f;
#pragma unroll
                for (int kt = 0; kt < 4; ++kt)
#pragma unroll
                    for (int r = 0; r < 4; ++r)
                        tmax = fmaxf(tmax, sT[kt][r]);
                tmax = fmaxf(tmax, __shfl_xor(tmax, 16));
                tmax = fmaxf(tmax, __shfl_xor(tmax, 32));
                float mn = fmaxf(m_i[sub], tmax);
                float alpha = exp2f(m_i[sub] - mn);
                m_i[sub] = mn;
                float rs = 0.0f;
                const int prow = wave * 32 + sub * 16 + l16;
#pragma unroll
                for (int kt = 0; kt < 4; ++kt) {
                    float p0 = exp2f(sT[kt][0] - mn);
                    float p1 = exp2f(sT[kt][1] - mn);
                    float p2 = exp2f(sT[kt][2] - mn);
                    float p3 = exp2f(sT[kt][3] - mn);
                    rs += (p0 + p1) + (p2 + p3);
                    short4v pk;
                    pk.x = f2bf(p0); pk.y = f2bf(p1);
                    pk.z = f2bf(p2); pk.w = f2bf(p3);
                    *(short4v*)&Ps[prow][kt * 16 + quad * 4] = pk;
                }
                rs += __shfl_xor(rs, 16);
                rs += __shfl_xor(rs, 32);
                l_i[sub] = l_i[sub] * alpha + rs;
#pragma unroll
                for (int dt = 0; dt < 4; ++dt) {
                    o[sub][dt][0] *= alpha; o[sub][dt][1] *= alpha;
                    o[sub][dt][2] *= alpha; o[sub][dt][3] *= alpha;
                }
            }

            // ---- O^T += V^T P^T ----
            bf16x8 Pf[2][2];
#pragma unroll
            for (int sub = 0; sub < 2; ++sub)
#pragma unroll
                for (int c = 0; c < 2; ++c)
                    Pf[sub][c] = *(const bf16x8*)
                        &Ps[wave * 32 + sub * 16 + l16][c * 32 + quad * 8];
#pragma unroll
            for (int c = 0; c < 2; ++c)
#pragma unroll
                for (int dt = 0; dt < 4; ++dt) {
                    bf16x8 av = *(const bf16x8*)
                        &Vt[dt * 16 + l16][c * 32 + quad * 8];
#pragma unroll
                    for (int sub = 0; sub < 2; ++sub)
                        o[sub][dt] = __builtin_amdgcn_mfma_f32_16x16x32_bf16(
                            av, Pf[sub][c], o[sub][dt], 0, 0, 0);
                }
        }
        __syncthreads();
    }

    // ---- epilogue: normalize, write bf16 (b, s, d) ----
    const int bi = bh >> 4;
    const int head = bh & 15;
#pragma unroll
    for (int sub = 0; sub < 2; ++sub) {
        const int q = qbase + sub * 16 + l16;
        const float linv = 1.0f / l_i[sub];
        short* ob = &O[((size_t)bi * S_LEN + q) * D_MODEL + head * DK];
#pragma unroll
        for (int dt = 0; dt < 4; ++dt) {
            short4v h;
            h.x = f2bf(o[sub][dt][0] * linv);
            h.y = f2bf(o[sub][dt][1] * linv);
            h.z = f2bf(o[sub][dt][2] * linv);
            h.w = f2bf(o[sub][dt][3] * linv);
            *(short4v*)&ob[dt * 16 + quad * 4] = h;
        }
    }
}

extern "C" void kernel_launch(void* const* d_in, const int* in_sizes, int n_in,
                              void* d_out, int out_size, void* d_ws, size_t ws_size,
                              hipStream_t stream) {
    const float* x  = (const float*)d_in[0];
    const float* Wq = (const float*)d_in[1];
    const float* Wk = (const float*)d_in[2];
    const float* Wv = (const float*)d_in[3];
    const float* Wo = (const float*)d_in[4];
    const int*   tp = (const int*)d_in[5];
    float* out = (float*)d_out;

    const int n  = BATCH * S_LEN * D_MODEL;       // 8388608
    const int nw = D_MODEL * D_MODEL;             // 1048576
    short* sw   = (short*)d_ws;
    short* xbf  = sw;
    short* Qbf  = sw + (size_t)n;
    short* Kbf  = sw + (size_t)2 * n;
    short* Vbf  = sw + (size_t)3 * n;
    short* Obf  = sw + (size_t)4 * n;
    short* Wqbf = sw + (size_t)5 * n;
    short* Wkbf = Wqbf + nw;
    short* Wvbf = Wkbf + nw;
    short* Wobf = Wvbf + nw;

    dim3 blk(256);
    conv_bf16<<<n / (256 * 8), blk, 0, stream>>>(x, xbf, n);
    conv_bf16<<<nw / (256 * 8), blk, 0, stream>>>(Wq, Wqbf, nw);
    conv_bf16<<<nw / (256 * 8), blk, 0, stream>>>(Wk, Wkbf, nw);
    conv_bf16<<<nw / (256 * 8), blk, 0, stream>>>(Wv, Wvbf, nw);
    conv_bf16<<<nw / (256 * 8), blk, 0, stream>>>(Wo, Wobf, nw);

    dim3 gproj(D_MODEL / 128, (BATCH * S_LEN) / 128);   // (8, 64)
    proj_bf16<1><<<gproj, blk, 0, stream>>>(xbf, Wqbf, tp, nullptr, Qbf, QSCALE);
    proj_bf16<1><<<gproj, blk, 0, stream>>>(xbf, Wkbf, tp, nullptr, Kbf, 1.0f);
    proj_bf16<2><<<gproj, blk, 0, stream>>>(xbf, Wvbf, tp, nullptr, Vbf, 1.0f);

    dim3 gattn(S_LEN / 128, BATCH * NH);                // (16, 64)
    attn_bf16<<<gattn, blk, 0, stream>>>(Qbf, Kbf, Vbf, Obf);

    proj_bf16<0><<<gproj, blk, 0, stream>>>(Obf, Wobf, tp, out, nullptr, 1.0f);
}

// Round 7
// 393.171 us; speedup vs baseline: 8.7306x; 1.1364x over previous
//
#include <hip/hip_runtime.h>
#include <math.h>

#define S_LEN 2048
#define D_MODEL 1024
#define NH 16
#define DK 64
#define BATCH 4

// log2(10000)/64
#define ROPE_L2F 0.20762050593046014f
// 0.125 * log2(e): folds 1/sqrt(dk) and exp->exp2 conversion into Q
#define QSCALE 0.18033688011112042f

typedef __attribute__((ext_vector_type(8))) short bf16x8;
typedef __attribute__((ext_vector_type(4))) short short4v;
typedef __attribute__((ext_vector_type(2))) short short2v;
typedef __attribute__((ext_vector_type(4))) float f32x4;

__device__ inline short f2bf(float f) {            // RNE fp32 -> bf16 bits
    unsigned u = __builtin_bit_cast(unsigned, f);
    unsigned r = u + 0x7FFFu + ((u >> 16) & 1u);
    return (short)(r >> 16);
}

// async global->LDS, 16B per lane; lds base must be wave-uniform.
__device__ inline void load_lds16(const void* g, void* l) {
    __builtin_amdgcn_global_load_lds(
        (const __attribute__((address_space(1))) unsigned int*)g,
        (__attribute__((address_space(3))) unsigned int*)l, 16, 0, 0);
}

// ---------------------------------------------------------------------------
// One-time fp32 -> bf16 conversions.
// ---------------------------------------------------------------------------
__global__ __launch_bounds__(256) void conv_bf16(
    const float* __restrict__ src, short* __restrict__ dst, int n)
{
    int i = (blockIdx.x * 256 + threadIdx.x) * 8;
    if (i >= n) return;
    float4 a = *(const float4*)&src[i];
    float4 b = *(const float4*)&src[i + 4];
    short h[8] = { f2bf(a.x), f2bf(a.y), f2bf(a.z), f2bf(a.w),
                   f2bf(b.x), f2bf(b.y), f2bf(b.z), f2bf(b.w) };
    *(bf16x8*)&dst[i] = *(bf16x8*)h;
}

__global__ __launch_bounds__(256) void conv_w4(
    const float* __restrict__ Wq, const float* __restrict__ Wk,
    const float* __restrict__ Wv, const float* __restrict__ Wo,
    short* __restrict__ dst)
{
    const float* srcs[4] = { Wq, Wk, Wv, Wo };
    const float* s = srcs[blockIdx.y];
    short* d = dst + (size_t)blockIdx.y * (D_MODEL * D_MODEL);
    int i = (blockIdx.x * 256 + threadIdx.x) * 8;
    float4 a = *(const float4*)&s[i];
    float4 b = *(const float4*)&s[i + 4];
    short h[8] = { f2bf(a.x), f2bf(a.y), f2bf(a.z), f2bf(a.w),
                   f2bf(b.x), f2bf(b.y), f2bf(b.z), f2bf(b.w) };
    *(bf16x8*)&d[i] = *(bf16x8*)h;
}

// ---------------------------------------------------------------------------
// bf16 MFMA GEMM, m97-style staging: C = A (Mx1024) @ B^T (1024x1024).
// 128x128 tile, BK=32, 4 waves 2x2. A/B tiles staged via global_load_lds
// (16B/lane, async, no VGPR round-trip). LDS unpadded [128][32] shorts;
// 16B chunks XOR-swizzled (phys = chunk ^ (row&3)) so frag ds_read_b128 is
// <=4-way. Staging geometry: wave w, call c covers rows w*32+c*16+(lane>>2);
// lane fetches global chunk (lane&3)^((lane>>2)&3) -> LDS phys chunk lane&3.
// MODE 0: fp32 row-major out (Wo). MODE 1: RoPE*scale -> bf16 (b,h,s,dk).
// MODE 2: bf16 (b,h,s,dk) (V).
// ---------------------------------------------------------------------------
template<int MODE>
__global__ __launch_bounds__(256) void proj_bf16(
    const short* __restrict__ A, const short* __restrict__ Bw,
    const int* __restrict__ tp, float* __restrict__ outf,
    short* __restrict__ outh, float scale)
{
    __shared__ short As[128][32];
    __shared__ short Bs[128][32];

    const int m0 = blockIdx.y * 128;
    const int n0 = blockIdx.x * 128;
    const int tid = threadIdx.x;
    const int lane = tid & 63;
    const int wave = tid >> 6;
    const int quad = lane >> 4;
    const int l16 = lane & 15;
    const int wr = (wave >> 1) * 64;
    const int wc = (wave & 1) * 64;

    // staging source pointers (advance by 32 shorts per k-step)
    const int srow = wave * 32 + (lane >> 2);
    const int schunk = (lane & 3) ^ ((lane >> 2) & 3);
    const short* agp = &A[(size_t)(m0 + srow) * D_MODEL + schunk * 8];
    const short* bgp = &Bw[(size_t)(n0 + srow) * D_MODEL + schunk * 8];
    short* alds0 = &As[wave * 32][0];
    short* alds1 = &As[wave * 32 + 16][0];
    short* blds0 = &Bs[wave * 32][0];
    short* blds1 = &Bs[wave * 32 + 16][0];

    const int fchunk = quad ^ (l16 & 3);   // phys chunk for frag reads

    f32x4 acc[4][4] = {};

    for (int k0 = 0; k0 < D_MODEL; k0 += 32) {
        load_lds16(agp, alds0);
        load_lds16(agp + 16 * D_MODEL, alds1);
        load_lds16(bgp, blds0);
        load_lds16(bgp + 16 * D_MODEL, blds1);
        agp += 32; bgp += 32;
        __syncthreads();

        bf16x8 a_h[4], b_h[4];
#pragma unroll
        for (int t = 0; t < 4; ++t) {
            a_h[t] = *(const bf16x8*)&As[wr + t * 16 + l16][fchunk * 8];
            b_h[t] = *(const bf16x8*)&Bs[wc + t * 16 + l16][fchunk * 8];
        }
#pragma unroll
        for (int mt = 0; mt < 4; ++mt)
#pragma unroll
            for (int nt = 0; nt < 4; ++nt)
                acc[mt][nt] = __builtin_amdgcn_mfma_f32_16x16x32_bf16(
                    a_h[mt], b_h[nt], acc[mt][nt], 0, 0, 0);
        __syncthreads();
    }

#pragma unroll
    for (int mt = 0; mt < 4; ++mt) {
#pragma unroll
        for (int r = 0; r < 4; ++r) {
            const int row = m0 + wr + mt * 16 + quad * 4 + r;
            if (MODE == 0) {
#pragma unroll
                for (int nt = 0; nt < 4; ++nt) {
                    int col = n0 + wc + nt * 16 + l16;
                    outf[(size_t)row * D_MODEL + col] = acc[mt][nt][r];
                }
            } else {
                const int bi = row >> 11;
                const int si = row & (S_LEN - 1);
                float pos = (float)tp[si];
#pragma unroll
                for (int nt = 0; nt < 4; ++nt) {
                    int col = n0 + wc + nt * 16 + l16;
                    int head = col >> 6;
                    int tloc = col & 63;
                    float v = acc[mt][nt][r];
                    float res;
                    if (MODE == 1) {
                        float partner = __shfl_xor(v, 1);
                        int tb = tloc & ~1;
                        float xe = (lane & 1) ? partner : v;
                        float xo = (lane & 1) ? v : partner;
                        float freq = exp2f(-(float)tb * ROPE_L2F);
                        float ang = pos * freq;
                        float s, c;
                        __sincosf(ang, &s, &c);
                        res = ((lane & 1) ? (s * xe + c * xo)
                                          : (c * xe - s * xo)) * scale;
                    } else {
                        res = v;
                    }
                    outh[(((size_t)bi * NH + head) * S_LEN + si) * DK + tloc] =
                        f2bf(res);
                }
            }
        }
    }
}

// ---------------------------------------------------------------------------
// MFMA flash causal attention, software-pipelined.
// Bq=128 (4 waves x 32 q rows), Bk=64. S^T = K*Q^T, O^T = V^T*P^T (q rides
// lane&15; softmax per-lane + 2 shfl). Vt double-buffered => ONE barrier
// per k-tile; next tile's K frags and V tile prefetched into registers
// during current tile's compute (hides L2/HBM latency).
// ---------------------------------------------------------------------------
#define PADS 72

__global__ __launch_bounds__(256) void attn_bf16(
    const short* __restrict__ Q, const short* __restrict__ K,
    const short* __restrict__ V, short* __restrict__ O)
{
    __shared__ short Vt[2][64][PADS];  // V tile transposed [d][k], dbuf
    __shared__ short Ps[128][PADS];    // P rows, wave-private

    const int bh = blockIdx.y;
    const int bx = (gridDim.x - 1) - blockIdx.x;   // heavy blocks first
    const int q0 = bx * 128;
    const int tid = threadIdx.x;
    const int wave = tid >> 6;
    const int lane = tid & 63;
    const int quad = lane >> 4;
    const int l16 = lane & 15;
    const int qbase = q0 + wave * 32;

    const short* Kb = K + (size_t)bh * S_LEN * DK;
    const short* Vb = V + (size_t)bh * S_LEN * DK;

    // Q fragments straight from global (wave-private rows)
    bf16x8 Qf[2][2];
#pragma unroll
    for (int sub = 0; sub < 2; ++sub)
#pragma unroll
        for (int c = 0; c < 2; ++c)
            Qf[sub][c] = *(const bf16x8*)
                &Q[((size_t)bh * S_LEN + qbase + sub * 16 + l16) * DK +
                   c * 32 + quad * 8];

    // V staging geometry (transpose via short2)
    const int kp2 = (tid & 31) * 2;
    const int db = (tid >> 5) * 8;

    // preload tile 0: V into regs, K frags into regs
    bf16x8 v0 = *(const bf16x8*)&Vb[(size_t)kp2 * DK + db];
    bf16x8 v1 = *(const bf16x8*)&Vb[(size_t)(kp2 + 1) * DK + db];
    bf16x8 Kf[4][2];
#pragma unroll
    for (int kt = 0; kt < 4; ++kt)
#pragma unroll
        for (int c = 0; c < 2; ++c)
            Kf[kt][c] = *(const bf16x8*)
                &Kb[(size_t)(kt * 16 + l16) * DK + c * 32 + quad * 8];

    float m_i[2] = { -1e30f, -1e30f }, l_i[2] = { 0.0f, 0.0f };
    f32x4 o[2][4] = {};

    const int ktiles = 2 * bx + 2;
    for (int t = 0; t < ktiles; ++t) {
        const int k0 = t * 64;
        const int buf = t & 1;
        // ---- commit prefetched V regs to Vt[buf] ----
#pragma unroll
        for (int i = 0; i < 8; ++i) {
            short2v p; p.x = v0[i]; p.y = v1[i];
            *(short2v*)&Vt[buf][db + i][kp2] = p;
        }
        __syncthreads();   // single barrier per tile (dbuf makes it safe)

        // ---- prefetch tile t+1 (V regs; K frags if this wave needs it) ----
        if (t + 1 < ktiles) {
            const short* vp = &Vb[(size_t)((t + 1) * 64 + kp2) * DK + db];
            v0 = *(const bf16x8*)vp;
            v1 = *(const bf16x8*)(vp + DK);
        }
        bf16x8 Kn[4][2];
        const bool need_next = (t + 1 < ktiles) && ((t + 1) * 64 <= qbase + 31);
        if (need_next) {
#pragma unroll
            for (int kt = 0; kt < 4; ++kt)
#pragma unroll
                for (int c = 0; c < 2; ++c)
                    Kn[kt][c] = *(const bf16x8*)
                        &Kb[(size_t)(k0 + 64 + kt * 16 + l16) * DK +
                            c * 32 + quad * 8];
        }

        if (k0 <= qbase + 31) {      // wave has live q rows for this tile
#pragma unroll
            for (int sub = 0; sub < 2; ++sub) {
                f32x4 sT[4] = {};
#pragma unroll
                for (int c = 0; c < 2; ++c)
#pragma unroll
                    for (int kt = 0; kt < 4; ++kt)
                        sT[kt] = __builtin_amdgcn_mfma_f32_16x16x32_bf16(
                            Kf[kt][c], Qf[sub][c], sT[kt], 0, 0, 0);

                const int qg = qbase + sub * 16 + l16;
                if (k0 + 63 > qbase + sub * 16) {   // causal mask needed
#pragma unroll
                    for (int kt = 0; kt < 4; ++kt)
#pragma unroll
                        for (int r = 0; r < 4; ++r)
                            if (k0 + kt * 16 + quad * 4 + r > qg)
                                sT[kt][r] = -1e30f;
                }

                // online softmax, exp2 domain, per-lane state
                float tmax = -1e30f;
#pragma unroll
                for (int kt = 0; kt < 4; ++kt)
#pragma unroll
                    for (int r = 0; r < 4; ++r)
                        tmax = fmaxf(tmax, sT[kt][r]);
                tmax = fmaxf(tmax, __shfl_xor(tmax, 16));
                tmax = fmaxf(tmax, __shfl_xor(tmax, 32));
                float mn = fmaxf(m_i[sub], tmax);
                float alpha = exp2f(m_i[sub] - mn);
                m_i[sub] = mn;
                float rs = 0.0f;
                const int prow = wave * 32 + sub * 16 + l16;
#pragma unroll
                for (int kt = 0; kt < 4; ++kt) {
                    float p0 = exp2f(sT[kt][0] - mn);
                    float p1 = exp2f(sT[kt][1] - mn);
                    float p2 = exp2f(sT[kt][2] - mn);
                    float p3 = exp2f(sT[kt][3] - mn);
                    rs += (p0 + p1) + (p2 + p3);
                    short4v pk;
                    pk.x = f2bf(p0); pk.y = f2bf(p1);
                    pk.z = f2bf(p2); pk.w = f2bf(p3);
                    *(short4v*)&Ps[prow][kt * 16 + quad * 4] = pk;
                }
                rs += __shfl_xor(rs, 16);
                rs += __shfl_xor(rs, 32);
                l_i[sub] = l_i[sub] * alpha + rs;
#pragma unroll
                for (int dt = 0; dt < 4; ++dt) {
                    o[sub][dt][0] *= alpha; o[sub][dt][1] *= alpha;
                    o[sub][dt][2] *= alpha; o[sub][dt][3] *= alpha;
                }
            }

            // ---- O^T += V^T P^T ----
            bf16x8 Pf[2][2];
#pragma unroll
            for (int sub = 0; sub < 2; ++sub)
#pragma unroll
                for (int c = 0; c < 2; ++c)
                    Pf[sub][c] = *(const bf16x8*)
                        &Ps[wave * 32 + sub * 16 + l16][c * 32 + quad * 8];
#pragma unroll
            for (int c = 0; c < 2; ++c)
#pragma unroll
                for (int dt = 0; dt < 4; ++dt) {
                    bf16x8 av = *(const bf16x8*)
                        &Vt[buf][dt * 16 + l16][c * 32 + quad * 8];
#pragma unroll
                    for (int sub = 0; sub < 2; ++sub)
                        o[sub][dt] = __builtin_amdgcn_mfma_f32_16x16x32_bf16(
                            av, Pf[sub][c], o[sub][dt], 0, 0, 0);
                }
        }

        if (need_next) {
#pragma unroll
            for (int kt = 0; kt < 4; ++kt)
#pragma unroll
                for (int c = 0; c < 2; ++c)
                    Kf[kt][c] = Kn[kt][c];
        }
    }

    // ---- epilogue: normalize, write bf16 (b, s, d) ----
    const int bi = bh >> 4;
    const int head = bh & 15;
#pragma unroll
    for (int sub = 0; sub < 2; ++sub) {
        const int q = qbase + sub * 16 + l16;
        const float linv = 1.0f / l_i[sub];
        short* ob = &O[((size_t)bi * S_LEN + q) * D_MODEL + head * DK];
#pragma unroll
        for (int dt = 0; dt < 4; ++dt) {
            short4v h;
            h.x = f2bf(o[sub][dt][0] * linv);
            h.y = f2bf(o[sub][dt][1] * linv);
            h.z = f2bf(o[sub][dt][2] * linv);
            h.w = f2bf(o[sub][dt][3] * linv);
            *(short4v*)&ob[dt * 16 + quad * 4] = h;
        }
    }
}

extern "C" void kernel_launch(void* const* d_in, const int* in_sizes, int n_in,
                              void* d_out, int out_size, void* d_ws, size_t ws_size,
                              hipStream_t stream) {
    const float* x  = (const float*)d_in[0];
    const float* Wq = (const float*)d_in[1];
    const float* Wk = (const float*)d_in[2];
    const float* Wv = (const float*)d_in[3];
    const float* Wo = (const float*)d_in[4];
    const int*   tp = (const int*)d_in[5];
    float* out = (float*)d_out;

    const int n  = BATCH * S_LEN * D_MODEL;       // 8388608
    const int nw = D_MODEL * D_MODEL;             // 1048576
    short* sw   = (short*)d_ws;
    short* xbf  = sw;
    short* Qbf  = sw + (size_t)n;
    short* Kbf  = sw + (size_t)2 * n;
    short* Vbf  = sw + (size_t)3 * n;
    short* Obf  = sw + (size_t)4 * n;
    short* Wqbf = sw + (size_t)5 * n;
    short* Wkbf = Wqbf + nw;
    short* Wvbf = Wkbf + nw;
    short* Wobf = Wvbf + nw;

    dim3 blk(256);
    conv_bf16<<<n / (256 * 8), blk, 0, stream>>>(x, xbf, n);
    dim3 gw(nw / (256 * 8), 4);
    conv_w4<<<gw, blk, 0, stream>>>(Wq, Wk, Wv, Wo, Wqbf);

    dim3 gproj(D_MODEL / 128, (BATCH * S_LEN) / 128);   // (8, 64)
    proj_bf16<1><<<gproj, blk, 0, stream>>>(xbf, Wqbf, tp, nullptr, Qbf, QSCALE);
    proj_bf16<1><<<gproj, blk, 0, stream>>>(xbf, Wkbf, tp, nullptr, Kbf, 1.0f);
    proj_bf16<2><<<gproj, blk, 0, stream>>>(xbf, Wvbf, tp, nullptr, Vbf, 1.0f);

    dim3 gattn(S_LEN / 128, BATCH * NH);                // (16, 64)
    attn_bf16<<<gattn, blk, 0, stream>>>(Qbf, Kbf, Vbf, Obf);

    proj_bf16<0><<<gproj, blk, 0, stream>>>(Obf, Wobf, tp, out, nullptr, 1.0f);
}